// Round 8
// baseline (88.246 us; speedup 1.0000x reference)
//
#include <hip/hip_runtime.h>

typedef unsigned int uint;
typedef unsigned short ushort;

#define BATCH 2048
#define INF_  512
#define OUTF  256
#define S_    8                 // K splits; K per block = 64 = 2 x BK32
#define NTILE 256               // (BATCH/64) * (OUTF/32)
#define PLANES_OFF 4096
#define CHUNK_ELEMS 2048        // 64x32 f16 per (tile, plane)
#define WS_NEED (PLANES_OFF + (size_t)NTILE * S_ * CHUNK_ELEMS * 2)

#define PKMIN(d, a, b) asm("v_pk_min_f16 %0, %1, %2" : "=v"(d) : "v"(a), "v"(b))
#define PKMAX(d, a, b) asm("v_pk_max_f16 %0, %1, %2" : "=v"(d) : "v"(a), "v"(b))
#define PKMAXA(d, a)   asm("v_pk_max_f16 %0, %0, %1" : "+v"(d) : "v"(a))

static __device__ __forceinline__ uint pkrtz(float a, float b) {
  typedef __fp16 half2_t __attribute__((ext_vector_type(2)));
  half2_t h = __builtin_amdgcn_cvt_pkrtz(a, b);
  return __builtin_bit_cast(uint, h);
}
static __device__ __forceinline__ float h2f(uint u) {
  __fp16 h = __builtin_bit_cast(__fp16, (ushort)(u & 0xFFFF));
  return (float)h;
}

// ONE kernel: convert + tropical partial + last-block combine.
// 1-wave block; wave tile 64 rows x 32 cols; per-thread 8x4; K/block = 64
// (2 x BK32, reg-staged cvt f32->f16, double-buffered). 2048 blocks = 8/CU.
// LDS f16 granules (uint4 = 8 k):
//   A[row][kq] at index row*4 + (kq ^ ((row>>3)&3))   (read: 2-way + broadcast)
//   B[col][kq] at index col*4 + (kq ^ ((col>>3)&3))   (read: 2-way + broadcast)
__global__ __launch_bounds__(64, 2) void crisp_fused(const float* __restrict__ M,
                                                     const float* __restrict__ W,
                                                     float* __restrict__ out,
                                                     uint* __restrict__ cnt,
                                                     ushort* __restrict__ planes) {
  __shared__ uint4 lsA[2][256];  // 64 rows x 4 kq-slots
  __shared__ uint4 lsB[2][128];  // 32 cols x 4 kq-slots

  const int lane = threadIdx.x;
  const int mg = lane >> 3;          // rows mg*8 + r
  const int og = lane & 7;           // cols og*4 + c
  const int row0 = blockIdx.y * 64;
  const int col0 = blockIdx.x * 32;
  const int z    = blockIdx.z;
  const int kb0  = z * 64;

  // staging assignment (per lane):
  // A: granules g = i*64+lane, i=0..3; row=g>>2, kq=(lane&3)^((row>>3)&3)
  // B: kqB=(lane>>3)&3, colq=lane&7, dup=lane>>5 -> cols c0=colq*4+dup*2, c0+1
  const int kqB  = (lane >> 3) & 3;
  const int colq = lane & 7;
  const int dup  = lane >> 5;
  const int cB0  = colq * 4 + dup * 2;

  float4 a[8];
  float2 b[8];

  auto issue = [&](int kb) {
#pragma unroll
    for (int i = 0; i < 4; i++) {
      int g = i * 64 + lane;
      int row = g >> 2;
      int kq = (lane & 3) ^ ((row >> 3) & 3);
      const float* p = M + (size_t)(row0 + row) * INF_ + kb + kq * 8;
      a[2 * i]     = *(const float4*)p;
      a[2 * i + 1] = *(const float4*)(p + 4);
    }
#pragma unroll
    for (int j = 0; j < 8; j++)
      b[j] = *(const float2*)(W + (size_t)(kb + kqB * 8 + j) * OUTF + col0 + cB0);
  };

  auto pack_write = [&](int buf) {
#pragma unroll
    for (int i = 0; i < 4; i++) {
      uint4 v;
      v.x = pkrtz(a[2 * i].x, a[2 * i].y);
      v.y = pkrtz(a[2 * i].z, a[2 * i].w);
      v.z = pkrtz(a[2 * i + 1].x, a[2 * i + 1].y);
      v.w = pkrtz(a[2 * i + 1].z, a[2 * i + 1].w);
      lsA[buf][i * 64 + lane] = v;  // linear -> conflict-free
    }
    uint4 g0, g1;  // granules for cols cB0, cB0+1 (k-pairs from row-wise loads)
    g0.x = pkrtz(b[0].x, b[1].x); g0.y = pkrtz(b[2].x, b[3].x);
    g0.z = pkrtz(b[4].x, b[5].x); g0.w = pkrtz(b[6].x, b[7].x);
    g1.x = pkrtz(b[0].y, b[1].y); g1.y = pkrtz(b[2].y, b[3].y);
    g1.z = pkrtz(b[4].y, b[5].y); g1.w = pkrtz(b[6].y, b[7].y);
    lsB[buf][cB0 * 4 + (kqB ^ ((cB0 >> 3) & 3))]             = g0;
    lsB[buf][(cB0 + 1) * 4 + (kqB ^ (((cB0 + 1) >> 3) & 3))] = g1;
  };

  uint acc[8][4];
#pragma unroll
  for (int r = 0; r < 8; r++)
#pragma unroll
    for (int c = 0; c < 4; c++) acc[r][c] = 0xFC00FC00u;  // packed f16 -inf

  auto compute = [&](int buf) {
#pragma unroll
    for (int kq = 0; kq < 4; kq++) {
      uint4 av[8], bv[4];
#pragma unroll
      for (int r = 0; r < 8; r++)
        av[r] = lsA[buf][(mg * 8 + r) * 4 + (kq ^ (mg & 3))];
#pragma unroll
      for (int c = 0; c < 4; c++) {
        int col = og * 4 + c;
        bv[c] = lsB[buf][col * 4 + (kq ^ ((col >> 3) & 3))];
      }
#pragma unroll
      for (int r = 0; r < 8; r++)
#pragma unroll
        for (int c = 0; c < 4; c++) {
          uint t0, t1, t2, t3;
          PKMIN(t0, av[r].x, bv[c].x);
          PKMIN(t1, av[r].y, bv[c].y);
          PKMIN(t2, av[r].z, bv[c].z);
          PKMIN(t3, av[r].w, bv[c].w);
          PKMAX(t0, t0, t1);
          PKMAX(t2, t2, t3);
          PKMAX(t0, t0, t2);
          PKMAXA(acc[r][c], t0);
        }
    }
  };

  issue(kb0);
  asm volatile("s_waitcnt vmcnt(0)" ::: "memory");
  pack_write(0);
  issue(kb0 + 32);        // in flight during compute(0)
  compute(0);
  asm volatile("s_waitcnt vmcnt(0)" ::: "memory");
  pack_write(1);
  compute(1);

  // ---- store f16 partial chunk (contiguous per (tile, plane)) ----
  const int t = blockIdx.y * (OUTF / 32) + blockIdx.x;  // 0..255
  ushort* chunk = planes + ((size_t)t * S_ + z) * CHUNK_ELEMS;
#pragma unroll
  for (int r = 0; r < 8; r++) {
    uint m0, m1, m2, m3;
    PKMAX(m0, acc[r][0], acc[r][0] >> 16);  // fold k-parity
    PKMAX(m1, acc[r][1], acc[r][1] >> 16);
    PKMAX(m2, acc[r][2], acc[r][2] >> 16);
    PKMAX(m3, acc[r][3], acc[r][3] >> 16);
    uint w0 = (m0 & 0xFFFFu) | (m1 << 16);
    uint w1 = (m2 & 0xFFFFu) | (m3 << 16);
    *(uint2*)(chunk + (mg * 8 + r) * 32 + og * 4) = make_uint2(w0, w1);
  }

  // ---- publish; last block per tile combines ----
  __threadfence();  // release: partial chunk visible device-wide
  uint old = 0;
  if (lane == 0) old = atomicAdd(&cnt[t], 1u);
  old = __shfl(old, 0);
  if (old == S_ - 1) {
    __threadfence();  // acquire: other XCDs' chunks visible
    const uint2* pb = (const uint2*)(planes + (size_t)t * S_ * CHUNK_ELEMS);
#pragma unroll
    for (int r = 0; r < 8; r++) {
      int idx = (mg * 8 + r) * 8 + og;  // uint2 index within plane (512/plane)
      uint2 v = pb[idx];
#pragma unroll
      for (int p = 1; p < S_; p++) {
        uint2 u = pb[p * 512 + idx];
        PKMAXA(v.x, u.x);
        PKMAXA(v.y, u.y);
      }
      float4 o = make_float4(h2f(v.x), h2f(v.x >> 16), h2f(v.y), h2f(v.y >> 16));
      *(float4*)&out[(size_t)(row0 + mg * 8 + r) * OUTF + col0 + og * 4] = o;
    }
  }
}

// ---- fallback: naive, correct ----
__global__ __launch_bounds__(256) void crisp_naive(const float* __restrict__ M,
                                                   const float* __restrict__ W,
                                                   float* __restrict__ out) {
  int o = blockIdx.x * 256 + threadIdx.x;
  int b = o >> 8, c = o & 255;
  float m = -1e30f;
  for (int k = 0; k < INF_; k++)
    m = fmaxf(m, fminf(M[(size_t)b * INF_ + k], W[(size_t)k * OUTF + c]));
  out[o] = m;
}

extern "C" void kernel_launch(void* const* d_in, const int* in_sizes, int n_in,
                              void* d_out, int out_size, void* d_ws, size_t ws_size,
                              hipStream_t stream) {
  const float* M = (const float*)d_in[0];
  const float* W = (const float*)d_in[1];
  float* out = (float*)d_out;

  if (ws_size >= WS_NEED) {
    uint* cnt = (uint*)d_ws;
    ushort* planes = (ushort*)((char*)d_ws + PLANES_OFF);
    hipMemsetAsync(d_ws, 0, NTILE * sizeof(uint), stream);  // reset tile counters
    crisp_fused<<<dim3(OUTF / 32, BATCH / 64, S_), 64, 0, stream>>>(M, W, out, cnt, planes);
  } else {
    crisp_naive<<<(BATCH * OUTF) / 256, 256, 0, stream>>>(M, W, out);
  }
}

// Round 9
// 19.472 us; speedup vs baseline: 4.5319x; 4.5319x over previous
//
#include <hip/hip_runtime.h>

typedef unsigned int uint;
typedef unsigned short ushort;

#define BATCH 2048
#define INF_  512
#define OUTF  256

#define PKMIN(d, a, b) asm("v_pk_min_f16 %0, %1, %2" : "=v"(d) : "v"(a), "v"(b))
#define PKMAXA(d, a)   asm("v_pk_max_f16 %0, %0, %1" : "+v"(d) : "v"(a))

static __device__ __forceinline__ uint pkrtz(float a, float b) {
  typedef __fp16 half2_t __attribute__((ext_vector_type(2)));
  half2_t h = __builtin_amdgcn_cvt_pkrtz(a, b);
  return __builtin_bit_cast(uint, h);
}
static __device__ __forceinline__ float h2flo(uint u) {
  __fp16 h = __builtin_bit_cast(__fp16, (ushort)(u & 0xFFFF));
  return (float)h;
}
static __device__ __forceinline__ float h2fhi(uint u) {
  __fp16 h = __builtin_bit_cast(__fp16, (ushort)(u >> 16));
  return (float)h;
}

// ONE kernel, ONE node, no workspace.
// Block: 256 threads = 4 waves; out-tile 32 rows x 32 cols; in-block K-split:
// wave w covers k in [w*128, w*128+128). Per-thread 4x4 outputs (c-packed f16).
// Grid 512 blocks = 2 blocks/CU (LDS 72KB), 8 waves/CU.
//
// LDS:
//  lsA: A f16 k-packed [row(32)][chunk(64)] (chunk = 8 k, 16B). Swizzle: chunk c of
//       row stored at (c&48) | ((c&15) ^ ((row>>2)&7)). Read av[r] hits 8 distinct
//       bank-groups across row-groups (cg broadcast) -> conflict-free.
//  lsB: B f16 col-paired [kpair(256)][cg(8)]: granule = {(c0,c1)k0,(c2,c3)k0,
//       (c0,c1)k1,(c2,c3)k1}. Read index %8 == cg -> conflict-free, rg broadcast.
//  lsR: 4 reduce planes (f16), folded by first 128 threads -> f32 out.
__global__ __launch_bounds__(256, 2)
void crisp_one(const float* __restrict__ M, const float* __restrict__ W,
               float* __restrict__ out) {
  __shared__ uint4 lsA[2048];  // 32 KB
  __shared__ uint4 lsB[2048];  // 32 KB
  __shared__ uint4 lsR[512];   // 8 KB

  const int t    = threadIdx.x;
  const int w    = t >> 6;
  const int lane = t & 63;
  const int rg   = lane >> 3;   // 0..7 -> rows rg*4 + r
  const int cg   = lane & 7;    // 0..7 -> cols cg*4 + c
  const int row0 = blockIdx.y * 32;
  const int col0 = blockIdx.x * 32;

  // ---- stage + convert (cooperative, coalesced, no transpose) ----
#pragma unroll
  for (int i = 0; i < 8; i++) {  // A: 2048 granules
    int g = i * 256 + t;
    int row = g >> 6, ch = g & 63;
    const float* p = M + (size_t)(row0 + row) * INF_ + ch * 8;
    float4 x = *(const float4*)p;
    float4 y = *(const float4*)(p + 4);
    uint4 v = make_uint4(pkrtz(x.x, x.y), pkrtz(x.z, x.w),
                         pkrtz(y.x, y.y), pkrtz(y.z, y.w));
    lsA[row * 64 + (ch & 48) + ((ch & 15) ^ ((row >> 2) & 7))] = v;
  }
#pragma unroll
  for (int i = 0; i < 8; i++) {  // B: 2048 granules (kpair, 4 cols)
    int g = i * 256 + t;
    int kp = g >> 3, cx = g & 7;
    const float* p0 = W + (size_t)(2 * kp) * OUTF + col0 + cx * 4;
    float4 r0 = *(const float4*)p0;
    float4 r1 = *(const float4*)(p0 + OUTF);
    lsB[g] = make_uint4(pkrtz(r0.x, r0.y), pkrtz(r0.z, r0.w),
                        pkrtz(r1.x, r1.y), pkrtz(r1.z, r1.w));
  }
  __syncthreads();

  // ---- compute: per-wave K-quarter, 4x4 outputs (2 packed col-pairs) ----
  uint acc[4][2];
#pragma unroll
  for (int r = 0; r < 4; r++) { acc[r][0] = 0xFC00FC00u; acc[r][1] = 0xFC00FC00u; }

#pragma unroll 2
  for (int kq = 0; kq < 16; kq++) {
    uint4 av[4];
#pragma unroll
    for (int r = 0; r < 4; r++)
      av[r] = lsA[(rg * 4 + r) * 64 + w * 16 + (kq ^ rg)];
#pragma unroll
    for (int kp = 0; kp < 4; kp++) {
      uint4 bv = lsB[(w * 64 + kq * 4 + kp) * 8 + cg];
#pragma unroll
      for (int r = 0; r < 4; r++) {
        uint wv = (kp == 0) ? av[r].x : (kp == 1) ? av[r].y
                  : (kp == 2) ? av[r].z : av[r].w;        // (k_even, k_odd)
        uint de = __builtin_amdgcn_perm(wv, wv, 0x01000100u);  // dup k_even
        uint dd = __builtin_amdgcn_perm(wv, wv, 0x03020302u);  // dup k_odd
        uint t0, t1, t2, t3;
        PKMIN(t0, de, bv.x);
        PKMIN(t1, de, bv.y);
        PKMIN(t2, dd, bv.z);
        PKMIN(t3, dd, bv.w);
        PKMAXA(acc[r][0], t0);
        PKMAXA(acc[r][1], t1);
        PKMAXA(acc[r][0], t2);
        PKMAXA(acc[r][1], t3);
      }
    }
  }

  // ---- in-block 4-way max-reduce across waves, then f32 store ----
  lsR[w * 128 + lane]      = make_uint4(acc[0][0], acc[0][1], acc[1][0], acc[1][1]);
  lsR[w * 128 + 64 + lane] = make_uint4(acc[2][0], acc[2][1], acc[3][0], acc[3][1]);
  __syncthreads();

  if (t < 128) {
    int q = t >> 6, ls = t & 63;
    uint4 v = lsR[q * 64 + ls];
#pragma unroll
    for (int ww = 1; ww < 4; ww++) {
      uint4 u = lsR[ww * 128 + q * 64 + ls];
      PKMAXA(v.x, u.x); PKMAXA(v.y, u.y); PKMAXA(v.z, u.z); PKMAXA(v.w, u.w);
    }
    int rbase = row0 + (ls >> 3) * 4 + q * 2;
    int cbase = col0 + (ls & 7) * 4;
    float4 o0 = make_float4(h2flo(v.x), h2fhi(v.x), h2flo(v.y), h2fhi(v.y));
    float4 o1 = make_float4(h2flo(v.z), h2fhi(v.z), h2flo(v.w), h2fhi(v.w));
    *(float4*)&out[(size_t)rbase * OUTF + cbase]       = o0;
    *(float4*)&out[(size_t)(rbase + 1) * OUTF + cbase] = o1;
  }
}

extern "C" void kernel_launch(void* const* d_in, const int* in_sizes, int n_in,
                              void* d_out, int out_size, void* d_ws, size_t ws_size,
                              hipStream_t stream) {
  const float* M = (const float*)d_in[0];
  const float* W = (const float*)d_in[1];
  float* out = (float*)d_out;
  crisp_one<<<dim3(OUTF / 32, BATCH / 32, 1), 256, 0, stream>>>(M, W, out);
}

// Round 10
// 18.654 us; speedup vs baseline: 4.7307x; 1.0439x over previous
//
#include <hip/hip_runtime.h>

typedef unsigned int uint;
typedef unsigned short ushort;

#define BATCH 2048
#define INF_  512
#define OUTF  256

#define PKMIN(d, a, b) asm("v_pk_min_f16 %0, %1, %2" : "=v"(d) : "v"(a), "v"(b))
#define PKMAXA(d, a)   asm("v_pk_max_f16 %0, %0, %1" : "+v"(d) : "v"(a))

// raw barrier (no implicit vmcnt drain -> in-flight global loads survive)
#define XBAR  asm volatile("s_barrier" ::: "memory")
#define LBAR  asm volatile("s_waitcnt lgkmcnt(0)\n\ts_barrier" ::: "memory")
#define VW0   asm volatile("s_waitcnt vmcnt(0)" ::: "memory")

static __device__ __forceinline__ uint pkrtz(float a, float b) {
  typedef __fp16 half2_t __attribute__((ext_vector_type(2)));
  half2_t h = __builtin_amdgcn_cvt_pkrtz(a, b);
  return __builtin_bit_cast(uint, h);
}
static __device__ __forceinline__ float h2flo(uint u) {
  __fp16 h = __builtin_bit_cast(__fp16, (ushort)(u & 0xFFFF));
  return (float)h;
}
static __device__ __forceinline__ float h2fhi(uint u) {
  __fp16 h = __builtin_bit_cast(__fp16, (ushort)(u >> 16));
  return (float)h;
}

// ONE kernel. Block 256 thr = 4 waves; out-tile 32x32; K split 8 ways
// (wave w x half-wave ks); per-thread 4 rows x 8 cols, K=16 per chunk.
// K chunks of 128, double-buffered; T14: global f32 loads for chunk c+1
// issued before compute of chunk c (regs), cvt+ds_write after raw barrier.
//
// LDS (16B granules = 8 f16, both k-packed (k_even,k_odd) pairs):
//  lsA[buf]: A [row(32)][g(16)] at row*16 + (g ^ (row>>2)); read av granule-col
//            = (g^rg)&7 -> 8 distinct across rg, cg broadcast, ks 2-way: free.
//  lsB[buf]: B [kpair(64)][cq(8)]: granule = 4 cols' k-pairs; read col = cq
//            (4 distinct, rg broadcast, ks 2-way): free. Writes linear.
// Reduce: 8 slice-planes (32x32 f16) in lsA region, tree-fold, f32 store.
__global__ __launch_bounds__(256, 2)
void crisp_one(const float* __restrict__ M, const float* __restrict__ W,
               float* __restrict__ out) {
  __shared__ uint4 lsA[2][512];  // 8 KB x2
  __shared__ uint4 lsB[2][512];  // 8 KB x2

  const int t    = threadIdx.x;
  const int w    = t >> 6;
  const int lane = t & 63;
  const int ks   = lane >> 5;         // half-wave K split
  const int rg   = (lane >> 2) & 7;   // rows rg*4 + r
  const int cg   = lane & 3;          // cols cg*8 .. +7
  const int s    = w * 2 + ks;        // k-slice 0..7 (16 k per chunk)
  const int row0 = blockIdx.y * 32;
  const int col0 = blockIdx.x * 32;

  float4 fa[4];  // A stage: 2 granules x 32B
  float4 fb[4];  // B stage: 2 granules x 2 rows x 16B

  auto issue = [&](int kc) {
#pragma unroll
    for (int j = 0; j < 2; j++) {
      int idx = j * 256 + t;
      int row = idx >> 4, g = idx & 15;
      const float* p = M + (size_t)(row0 + row) * INF_ + kc * 128 + g * 8;
      fa[2 * j]     = *(const float4*)p;
      fa[2 * j + 1] = *(const float4*)(p + 4);
      int kp = idx >> 3, cq = idx & 7;
      const float* q = W + (size_t)(kc * 128 + 2 * kp) * OUTF + col0 + cq * 4;
      fb[2 * j]     = *(const float4*)q;
      fb[2 * j + 1] = *(const float4*)(q + OUTF);
    }
  };

  auto pack = [&](int buf) {
#pragma unroll
    for (int j = 0; j < 2; j++) {
      int idx = j * 256 + t;
      int row = idx >> 4, g = idx & 15;
      lsA[buf][row * 16 + (g ^ (row >> 2))] =
          make_uint4(pkrtz(fa[2 * j].x, fa[2 * j].y),
                     pkrtz(fa[2 * j].z, fa[2 * j].w),
                     pkrtz(fa[2 * j + 1].x, fa[2 * j + 1].y),
                     pkrtz(fa[2 * j + 1].z, fa[2 * j + 1].w));
      lsB[buf][idx] =  // packed-k per column: (k_even, k_odd)
          make_uint4(pkrtz(fb[2 * j].x, fb[2 * j + 1].x),
                     pkrtz(fb[2 * j].y, fb[2 * j + 1].y),
                     pkrtz(fb[2 * j].z, fb[2 * j + 1].z),
                     pkrtz(fb[2 * j].w, fb[2 * j + 1].w));
    }
  };

  uint acc[4][8];  // packed k-parity accumulators
#pragma unroll
  for (int r = 0; r < 4; r++)
#pragma unroll
    for (int c = 0; c < 8; c++) acc[r][c] = 0xFC00FC00u;

  auto compute = [&](int buf) {
#pragma unroll
    for (int kq = 0; kq < 2; kq++) {
      uint4 av[4];
#pragma unroll
      for (int r = 0; r < 4; r++)
        av[r] = lsA[buf][(rg * 4 + r) * 16 + ((s * 2 + kq) ^ rg)];
#pragma unroll
      for (int kpl = 0; kpl < 4; kpl++) {
        uint4 bv0 = lsB[buf][(s * 8 + kq * 4 + kpl) * 8 + cg * 2];
        uint4 bv1 = lsB[buf][(s * 8 + kq * 4 + kpl) * 8 + cg * 2 + 1];
#pragma unroll
        for (int r = 0; r < 4; r++) {
          uint a = (kpl == 0) ? av[r].x : (kpl == 1) ? av[r].y
                   : (kpl == 2) ? av[r].z : av[r].w;
          uint t0, t1, t2, t3, t4, t5, t6, t7;
          PKMIN(t0, a, bv0.x); PKMIN(t1, a, bv0.y);
          PKMIN(t2, a, bv0.z); PKMIN(t3, a, bv0.w);
          PKMIN(t4, a, bv1.x); PKMIN(t5, a, bv1.y);
          PKMIN(t6, a, bv1.z); PKMIN(t7, a, bv1.w);
          PKMAXA(acc[r][0], t0); PKMAXA(acc[r][1], t1);
          PKMAXA(acc[r][2], t2); PKMAXA(acc[r][3], t3);
          PKMAXA(acc[r][4], t4); PKMAXA(acc[r][5], t5);
          PKMAXA(acc[r][6], t6); PKMAXA(acc[r][7], t7);
        }
      }
    }
  };

  // ---- pipelined chunks: issue(c+1) flies under compute(c) ----
  issue(0); VW0; pack(0); LBAR;
  issue(1);
  compute(0); VW0; pack(1); LBAR;
  issue(2);
  compute(1); VW0; pack(0); LBAR;
  issue(3);
  compute(0); VW0; pack(1); LBAR;
  compute(1);
  XBAR;  // all waves done with lsA/lsB

  // ---- reduce: 8 slice-planes in lsA region ----
  uint* lsu = (uint*)lsA;  // 4096 uints = 8 planes x 512
#pragma unroll
  for (int r = 0; r < 4; r++) {
    uint m[8];
#pragma unroll
    for (int c = 0; c < 8; c++) {
      PKMAXA(acc[r][c], acc[r][c] >> 16);  // low16 = max(k_even, k_odd)
      m[c] = acc[r][c] & 0xFFFFu;
    }
    uint4 v = make_uint4(m[0] | (m[1] << 16), m[2] | (m[3] << 16),
                         m[4] | (m[5] << 16), m[6] | (m[7] << 16));
    ((uint4*)lsu)[s * 128 + (rg * 4 + r) * 4 + cg] = v;
  }
  LBAR;

  {
    uint2 v = ((const uint2*)lsu)[t];
#pragma unroll
    for (int p = 1; p < 8; p++) {
      uint2 u = ((const uint2*)lsu)[p * 256 + t];
      PKMAXA(v.x, u.x);
      PKMAXA(v.y, u.y);
    }
    int row = t >> 3, col = (t & 7) * 4;
    float4 o = make_float4(h2flo(v.x), h2fhi(v.x), h2flo(v.y), h2fhi(v.y));
    *(float4*)&out[(size_t)(row0 + row) * OUTF + col0 + col] = o;
  }
}

extern "C" void kernel_launch(void* const* d_in, const int* in_sizes, int n_in,
                              void* d_out, int out_size, void* d_ws, size_t ws_size,
                              hipStream_t stream) {
  const float* M = (const float*)d_in[0];
  const float* W = (const float*)d_in[1];
  float* out = (float*)d_out;
  crisp_one<<<dim3(OUTF / 32, BATCH / 32, 1), 256, 0, stream>>>(M, W, out);
}

// Round 11
// 17.439 us; speedup vs baseline: 5.0603x; 1.0697x over previous
//
#include <hip/hip_runtime.h>

typedef unsigned int uint;
typedef unsigned short ushort;

#define BATCH 2048
#define INF_  512
#define OUTF  256

#define PKMIN(d, a, b) asm("v_pk_min_f16 %0, %1, %2" : "=v"(d) : "v"(a), "v"(b))
#define PKMAXA(d, a)   asm("v_pk_max_f16 %0, %0, %1" : "+v"(d) : "v"(a))

#define VW0   asm volatile("s_waitcnt vmcnt(0)" ::: "memory")
#define LBAR  asm volatile("s_waitcnt lgkmcnt(0)\n\ts_barrier" ::: "memory")
#define XBAR  asm volatile("s_barrier" ::: "memory")

static __device__ __forceinline__ uint pkrtz(float a, float b) {
  typedef __fp16 half2_t __attribute__((ext_vector_type(2)));
  half2_t h = __builtin_amdgcn_cvt_pkrtz(a, b);
  return __builtin_bit_cast(uint, h);
}
static __device__ __forceinline__ float h2flo(uint u) {
  __fp16 h = __builtin_bit_cast(__fp16, (ushort)(u & 0xFFFF));
  return (float)h;
}
static __device__ __forceinline__ float h2fhi(uint u) {
  __fp16 h = __builtin_bit_cast(__fp16, (ushort)(u >> 16));
  return (float)h;
}

// ONE kernel, ONE node. Block = 512 threads (8 waves); out-tile 32x32.
// K=512 split 16 ways in-block: slice s = wave*2 + halfwave, 32 k each.
// Per-thread 4 rows x 8 cols, 32 k -> 1024 pk instr. Whole K staged ONCE
// (no chunk loop): 16 float4 loads/thread -> vmcnt(0) -> pack -> barrier ->
// compute -> barrier -> LDS tree-reduce over 16 slices -> f32 store.
// Grid 512 blocks = 2/CU (LDS 64KB) = 16 waves/CU = 4/SIMD.
//
// LDS (16B granules = 4 packed (k_even,k_odd) f16 pairs):
//  lsA[row(32)][slot(64)]: granule g (k 8g..8g+7) at slot (g&56)|((g^(row>>2))&7)
//    -> read av: 8 distinct bank-quads across rg, cg broadcast, ks 2-way: free.
//  lsB[kp(256)][cq(8)]: granule = 4 cols' pair kp; linear. read: rg broadcast,
//    4 quads x (2 ks) = 2-way: free.
// XCD swizzle (T1): bid = c + 8x + 64m -> tile x, y = 8c + m; xcd = bid%8 = c
// -> the 8 x-blocks sharing an M-slab co-reside on one XCD's L2.
__global__ __launch_bounds__(512, 4)
void crisp_one(const float* __restrict__ M, const float* __restrict__ W,
               float* __restrict__ out) {
  __shared__ uint4 lsA[2048];  // 32 KB
  __shared__ uint4 lsB[2048];  // 32 KB

  const int t    = threadIdx.x;
  const int w    = t >> 6;
  const int lane = t & 63;
  const int ks   = lane >> 5;
  const int rg   = (lane >> 2) & 7;  // rows rg*4 + r
  const int cg   = lane & 3;         // cols cg*8 .. +7
  const int s    = w * 2 + ks;       // k-slice 0..15

  const int bid  = blockIdx.x;
  const int row0 = (((bid & 7) << 3) | (bid >> 6)) * 32;
  const int col0 = ((bid >> 3) & 7) * 32;

  // ---- stage: issue ALL global loads, then one drain ----
  float4 fa[8], fb[8];
#pragma unroll
  for (int j = 0; j < 4; j++) {
    int idx = j * 512 + t;           // A granule 0..2047
    int row = idx >> 6, g = idx & 63;
    const float* p = M + (size_t)(row0 + row) * INF_ + g * 8;
    fa[2 * j]     = *(const float4*)p;
    fa[2 * j + 1] = *(const float4*)(p + 4);
  }
#pragma unroll
  for (int j = 0; j < 4; j++) {
    int idx = j * 512 + t;           // B granule 0..2047
    int kp = idx >> 3, cq = idx & 7;
    const float* q = W + (size_t)(2 * kp) * OUTF + col0 + cq * 4;
    fb[2 * j]     = *(const float4*)q;
    fb[2 * j + 1] = *(const float4*)(q + OUTF);
  }
  VW0;
  // ---- pack f32 -> packed-pair f16, write LDS ----
#pragma unroll
  for (int j = 0; j < 4; j++) {
    int idx = j * 512 + t;
    int row = idx >> 6, g = idx & 63;
    int slot = (g & 56) | ((g ^ (row >> 2)) & 7);
    lsA[row * 64 + slot] = make_uint4(
        pkrtz(fa[2 * j].x, fa[2 * j].y), pkrtz(fa[2 * j].z, fa[2 * j].w),
        pkrtz(fa[2 * j + 1].x, fa[2 * j + 1].y),
        pkrtz(fa[2 * j + 1].z, fa[2 * j + 1].w));
    lsB[idx] = make_uint4(                       // (k_even,k_odd) per col
        pkrtz(fb[2 * j].x, fb[2 * j + 1].x), pkrtz(fb[2 * j].y, fb[2 * j + 1].y),
        pkrtz(fb[2 * j].z, fb[2 * j + 1].z), pkrtz(fb[2 * j].w, fb[2 * j + 1].w));
  }
  LBAR;

  // ---- compute: slice s (granules 4s..4s+3), 4r x 8c ----
  uint acc[4][8];
#pragma unroll
  for (int r = 0; r < 4; r++)
#pragma unroll
    for (int c = 0; c < 8; c++) acc[r][c] = 0xFC00FC00u;

#pragma unroll
  for (int gq = 0; gq < 4; gq++) {
    const int g = s * 4 + gq;
    uint4 av[4];
#pragma unroll
    for (int r = 0; r < 4; r++)
      av[r] = lsA[(rg * 4 + r) * 64 + ((g & 56) | ((g ^ rg) & 7))];
#pragma unroll
    for (int kpl = 0; kpl < 4; kpl++) {
      const int kp = g * 4 + kpl;
      uint4 bv0 = lsB[kp * 8 + cg * 2];
      uint4 bv1 = lsB[kp * 8 + cg * 2 + 1];
#pragma unroll
      for (int r = 0; r < 4; r++) {
        uint a = (kpl == 0) ? av[r].x : (kpl == 1) ? av[r].y
                 : (kpl == 2) ? av[r].z : av[r].w;
        uint t0, t1, t2, t3, t4, t5, t6, t7;
        PKMIN(t0, a, bv0.x); PKMIN(t1, a, bv0.y);
        PKMIN(t2, a, bv0.z); PKMIN(t3, a, bv0.w);
        PKMIN(t4, a, bv1.x); PKMIN(t5, a, bv1.y);
        PKMIN(t6, a, bv1.z); PKMIN(t7, a, bv1.w);
        PKMAXA(acc[r][0], t0); PKMAXA(acc[r][1], t1);
        PKMAXA(acc[r][2], t2); PKMAXA(acc[r][3], t3);
        PKMAXA(acc[r][4], t4); PKMAXA(acc[r][5], t5);
        PKMAXA(acc[r][6], t6); PKMAXA(acc[r][7], t7);
      }
    }
  }
  XBAR;  // all waves done reading lsA/lsB (reads consumed => lgkm drained)

  // ---- reduce: 16 slice-planes (32x32 f16 = 2KB) in lsA region ----
  uint* pl = (uint*)lsA + s * 512;
#pragma unroll
  for (int r = 0; r < 4; r++) {
    uint m[8];
#pragma unroll
    for (int c = 0; c < 8; c++) {
      uint hi = acc[r][c] >> 16;
      PKMAXA(acc[r][c], hi);           // low16 = max(k_even, k_odd)
      m[c] = acc[r][c] & 0xFFFFu;
    }
    ((uint4*)pl)[(rg * 4 + r) * 4 + cg] = make_uint4(
        m[0] | (m[1] << 16), m[2] | (m[3] << 16),
        m[4] | (m[5] << 16), m[6] | (m[7] << 16));
  }
  LBAR;

  if (t < 256) {  // fold 16 planes, 4 outputs/thread, f32 store
    uint2 v = ((const uint2*)lsA)[t];
#pragma unroll
    for (int p = 1; p < 16; p++) {
      uint2 u = ((const uint2*)lsA)[p * 256 + t];
      PKMAXA(v.x, u.x);
      PKMAXA(v.y, u.y);
    }
    int row = t >> 3, col = (t & 7) * 4;
    *(float4*)&out[(size_t)(row0 + row) * OUTF + col0 + col] =
        make_float4(h2flo(v.x), h2fhi(v.x), h2flo(v.y), h2fhi(v.y));
  }
}

extern "C" void kernel_launch(void* const* d_in, const int* in_sizes, int n_in,
                              void* d_out, int out_size, void* d_ws, size_t ws_size,
                              hipStream_t stream) {
  const float* M = (const float*)d_in[0];
  const float* W = (const float*)d_in[1];
  float* out = (float*)d_out;
  crisp_one<<<512, 512, 0, stream>>>(M, W, out);
}